// Round 1
// baseline (412.065 us; speedup 1.0000x reference)
//
#include <hip/hip_runtime.h>

// LambdaReturn: reverse-time linear recurrence
//   delta_t = r_t + DISCOUNT*(1-LAMBD)*m_t*v_t
//   ret_t   = delta_t + (DISCOUNT*LAMBD)*m_t*carry,   carry <- ret_t
//   carry init = v_{T-1}
// T=1000, B=32768, fp32. One thread per column; unroll-8 so the compiler
// batches the (carry-independent) loads for latency hiding at 2 waves/CU.

#define T_DIM 1000
#define B_DIM 32768

__global__ __launch_bounds__(64) void LambdaReturn_kernel(
    const float* __restrict__ rewards,
    const float* __restrict__ values,
    const float* __restrict__ masks,
    float* __restrict__ out) {
  const int b = blockIdx.x * blockDim.x + threadIdx.x;
  const float c_delta = 0.99f * (1.0f - 0.95f);  // gamma*(1-lambda)
  const float gl      = 0.99f * 0.95f;           // gamma*lambda

  float carry = values[(size_t)(T_DIM - 1) * B_DIM + b];

  // reverse-time scan; 1000 = 125 * 8
  #pragma unroll 8
  for (int t = T_DIM - 1; t >= 0; --t) {
    const size_t idx = (size_t)t * B_DIM + b;
    const float r = rewards[idx];
    const float v = values[idx];
    const float m = masks[idx];
    const float d = fmaf(c_delta * m, v, r);
    carry = fmaf(gl * m, carry, d);
    out[idx] = carry;
  }
}

extern "C" void kernel_launch(void* const* d_in, const int* in_sizes, int n_in,
                              void* d_out, int out_size, void* d_ws, size_t ws_size,
                              hipStream_t stream) {
  const float* rewards = (const float*)d_in[0];
  const float* values  = (const float*)d_in[1];
  const float* masks   = (const float*)d_in[2];
  float* out = (float*)d_out;

  dim3 grid(B_DIM / 64);
  dim3 block(64);
  LambdaReturn_kernel<<<grid, block, 0, stream>>>(rewards, values, masks, out);
}

// Round 2
// 365.142 us; speedup vs baseline: 1.1285x; 1.1285x over previous
//
#include <hip/hip_runtime.h>

// LambdaReturn: reverse-time linear recurrence, T=1000, B=32768, fp32.
//   delta_t = r_t + g*(1-l)*m_t*v_t ;  ret_t = delta_t + g*l*m_t*carry
// One thread per column (512 wave64 = 2 waves/CU). Latency-bound at VGPR=24
// in R1 (1.9 TB/s) -> explicit double-buffered register pipeline, U=20
// timesteps per group, 50 groups, ping-pong A/B. Keeps 60-120 dword loads
// in flight per wave (~15-30 KB/CU vs 9.2 KB needed for 6.3 TB/s).

#define T_DIM 1000
#define B_DIM 32768
#define U 20          // timesteps per group; 1000 = 50 * 20
#define NGROUPS 50

__global__ __launch_bounds__(64) void LambdaReturn_kernel(
    const float* __restrict__ rewards,
    const float* __restrict__ values,
    const float* __restrict__ masks,
    float* __restrict__ out) {
  const int b = blockIdx.x * blockDim.x + threadIdx.x;
  const float c_delta = 0.99f * (1.0f - 0.95f);  // gamma*(1-lambda)
  const float gl      = 0.99f * 0.95f;           // gamma*lambda

  const float* pr = rewards + b;
  const float* pv = values + b;
  const float* pm = masks + b;
  float* po = out + b;

  float carry = pv[(size_t)(T_DIM - 1) * B_DIM];

  float rA[U], vA[U], mA[U];
  float rB[U], vB[U], mB[U];

  // group g covers t = (999 - U*g) down to (999 - U*g - (U-1)), j = 0..U-1
  auto ld = [&](float* r, float* v, float* m, int g) {
    const size_t base = (size_t)(T_DIM - 1 - U * g) * B_DIM;
    #pragma unroll
    for (int j = 0; j < U; ++j) {
      const size_t idx = base - (size_t)j * B_DIM;
      r[j] = __builtin_nontemporal_load(pr + idx);
      v[j] = __builtin_nontemporal_load(pv + idx);
      m[j] = __builtin_nontemporal_load(pm + idx);
    }
  };
  auto cmp = [&](const float* r, const float* v, const float* m, int g) {
    const size_t base = (size_t)(T_DIM - 1 - U * g) * B_DIM;
    #pragma unroll
    for (int j = 0; j < U; ++j) {
      const float d = fmaf(c_delta * m[j], v[j], r[j]);
      carry = fmaf(gl * m[j], carry, d);
      __builtin_nontemporal_store(carry, po + (base - (size_t)j * B_DIM));
    }
  };

  ld(rA, vA, mA, 0);
  ld(rB, vB, mB, 1);

  for (int g = 0; g < NGROUPS - 2; g += 2) {
    cmp(rA, vA, mA, g);         // waits on A (issued 2 groups ago)
    ld(rA, vA, mA, g + 2);      // refill A, overlaps B's compute
    cmp(rB, vB, mB, g + 1);
    if (g + 3 < NGROUPS) ld(rB, vB, mB, g + 3);
  }
  cmp(rA, vA, mA, NGROUPS - 2);
  cmp(rB, vB, mB, NGROUPS - 1);
}

extern "C" void kernel_launch(void* const* d_in, const int* in_sizes, int n_in,
                              void* d_out, int out_size, void* d_ws, size_t ws_size,
                              hipStream_t stream) {
  const float* rewards = (const float*)d_in[0];
  const float* values  = (const float*)d_in[1];
  const float* masks   = (const float*)d_in[2];
  float* out = (float*)d_out;

  dim3 grid(B_DIM / 64);
  dim3 block(64);
  LambdaReturn_kernel<<<grid, block, 0, stream>>>(rewards, values, masks, out);
}